// Round 5
// baseline (165.034 us; speedup 1.0000x reference)
//
#include <hip/hip_runtime.h>
#include <hip/hip_bf16.h>

#define BSZ   8
#define NQ    1000
#define DM    256
#define MROWS (BSZ*NQ)
#define TOPK  10
#define NTILE (MROWS/16)    // 500 MLP tiles

typedef __attribute__((ext_vector_type(8))) short short8;
typedef __attribute__((ext_vector_type(4))) float f32x4;
typedef unsigned short u16;
typedef unsigned int   u32;

static __device__ __forceinline__ float b2f(u16 u) { return __uint_as_float(((u32)u) << 16); }
static __device__ __forceinline__ u16 f2b(float f) {
    __hip_bfloat16 h = __float2bfloat16(f);   // RNE
    return *(u16*)&h;
}
// monotonic order-preserving float<->uint encoding (for atomicMax-based fmax)
static __device__ __forceinline__ u32 encf(float f) {
    u32 u = __float_as_uint(f);
    return (u & 0x80000000u) ? ~u : (u | 0x80000000u);
}
static __device__ __forceinline__ float decf(u32 e) {
    u32 u = (e & 0x80000000u) ? (e ^ 0x80000000u) : ~e;
    return __uint_as_float(u);
}

// ============ K0: weight prep — f32 W[k][n] -> bf16 WT[n][k] (transposed) ====
__global__ __launch_bounds__(256) void prep_k(
    const float* __restrict__ W1, const float* __restrict__ W2,
    const float* __restrict__ W3, const float* __restrict__ W4,
    const float* __restrict__ W5, u16* __restrict__ WT)
{
    const int m  = blockIdx.x >> 4;
    const int kb = (blockIdx.x & 15) * 16;
    const float* W = (m==0)?W1:(m==1)?W2:(m==2)?W3:(m==3)?W4:W5;
    u16* D = WT + (size_t)m * DM * DM;
    const int t = threadIdx.x;           // n
    u16 tmp[16];
    #pragma unroll
    for (int kk = 0; kk < 16; ++kk)
        tmp[kk] = f2b(W[(size_t)(kb+kk)*DM + t]);    // coalesced read
    #pragma unroll
    for (int kk = 0; kk < 16; ++kk)
        D[(size_t)t*DM + kb + kk] = tmp[kk];         // 32B contiguous/thread
}

// ============ shared 16x256x256 block-GEMM (MFMA 16x16x32 bf16) ==============
// A is a [16][264] bf16 LDS tile. B fragments are loaded DIRECTLY from the
// pre-transposed WT[n][k] in global (L2-resident): each (n,k) element is
// consumed by exactly one lane of one wave, so LDS staging had zero reuse —
// dropping it removes 36.9KB LDS (occupancy 2->4+ blocks/CU) and 7 of 8
// barriers per GEMM. MFMA order (kc->ks->nt) unchanged => bit-identical.
// Epilogue variants:
//   0: relu(acc+bias) -> OutL    1: acc+bias -> OutL
//   2: acc -> OutG (bf16 global) 3: final residual -> OutF (f32 global)
template<int EPI>
static __device__ __forceinline__ void block_gemm256(
    const u16 (*__restrict__ A)[264], const u16* __restrict__ WT,
    const float* __restrict__ bias, u16 (*__restrict__ OutL)[264],
    u16* __restrict__ OutG, float* __restrict__ OutF,
    const float* __restrict__ tgt, const float* __restrict__ seed,
    int r0, int t)
{
    const int lane = t & 63, wave = t >> 6;
    const int m = lane & 15, quad = lane >> 4;
    f32x4 acc[4];
    #pragma unroll
    for (int nt = 0; nt < 4; ++nt)
        #pragma unroll
        for (int i = 0; i < 4; ++i) acc[nt][i] = 0.f;
    __syncthreads();   // A tile ready (and prior users of the A buffer done)
    const u16* Wb = WT + (size_t)(wave*64 + m)*DM + quad*8;
    for (int kc = 0; kc < 4; ++kc) {
        #pragma unroll
        for (int ks = 0; ks < 2; ++ks) {
            const short8 a = *(const short8*)&A[m][kc*64 + ks*32 + quad*8];
            #pragma unroll
            for (int nt = 0; nt < 4; ++nt) {
                const short8 b = *(const short8*)&Wb[(size_t)nt*16*DM + kc*64 + ks*32];
                acc[nt] = __builtin_amdgcn_mfma_f32_16x16x32_bf16(a, b, acc[nt], 0, 0, 0);
            }
        }
    }
    // C/D: row = quad*4+reg, col = wave*64+nt*16+m  (verified R4/R5)
    #pragma unroll
    for (int nt = 0; nt < 4; ++nt) {
        const int n = wave*64 + nt*16 + m;
        const float bb = bias ? bias[n] : 0.f;
        #pragma unroll
        for (int reg = 0; reg < 4; ++reg) {
            const int rl = quad*4 + reg;
            float v = acc[nt][reg] + bb;
            if (EPI == 0) OutL[rl][n] = f2b(fmaxf(v, 0.f));
            if (EPI == 1) OutL[rl][n] = f2b(v);
            if (EPI == 2) OutG[(size_t)(r0+rl)*DM + n] = f2b(v);
            if (EPI == 3) {
                const int R = r0 + rl;
                OutF[(size_t)R*DM + n] = tgt[(size_t)R*DM + n]
                                       + fmaxf(v, 0.f) * (1.f - seed[R]);
            }
        }
    }
}

// LDS overlay: MLP tiles need 16.9KB (bufA+bufB only now); IoU rows 8KB.
struct MlpSmem { u16 bufA[16][264]; u16 bufB[16][264]; };
struct IouSmem { float sv[NQ]; int sj[NQ]; int scount; };

// ============ K12: fused MLP chain (blocks 0..499) + IoU rows (500..8499) ====
__global__ __launch_bounds__(256, 4) void fused_iou_mlp_k(
    const float* __restrict__ boxes, const float* __restrict__ seed,
    const u16* __restrict__ WT,
    const float* __restrict__ b1, const float* __restrict__ b2,
    const float* __restrict__ g2, const float* __restrict__ be2,
    const float* __restrict__ tgt,
    u16* __restrict__ P, float* __restrict__ attn,
    int* __restrict__ cnt, int* __restrict__ inc0, int* __restrict__ idxs)
{
    __shared__ __align__(16) unsigned char smraw[sizeof(MlpSmem)];
    const int t = threadIdx.x;
    const int bid = blockIdx.x;

    if (bid < NTILE) {
        // ---------------- MLP tile: tgt -> H -> Y -> LN -> P ----------------
        MlpSmem& sm = *reinterpret_cast<MlpSmem*>(smraw);
        const int r0 = bid * 16;
        const int lane = t & 63, wave = t >> 6;
        const u16* W1T = WT;
        const u16* W2T = WT + (size_t)1*DM*DM;
        const u16* W3T = WT + (size_t)2*DM*DM;

        // stage tgt f32 -> bufA bf16 (thread t: row t>>4, 16 cols from (t&15)*16)
        {
            const int r = t >> 4, c0 = (t & 15) * 16;
            const float* src = &tgt[(size_t)(r0 + r)*DM + c0];
            __align__(16) u16 h[16];
            #pragma unroll
            for (int q = 0; q < 4; ++q) {
                const float4 f = *(const float4*)&src[q*4];
                h[q*4+0] = f2b(f.x); h[q*4+1] = f2b(f.y);
                h[q*4+2] = f2b(f.z); h[q*4+3] = f2b(f.w);
            }
            *(uint4*)&sm.bufA[r][c0]     = *(uint4*)&h[0];
            *(uint4*)&sm.bufA[r][c0 + 8] = *(uint4*)&h[8];
        }

        block_gemm256<0>(sm.bufA, W1T, b1, sm.bufB,
                         nullptr, nullptr, nullptr, nullptr, r0, t); // H
        block_gemm256<1>(sm.bufB, W2T, b2, sm.bufA,
                         nullptr, nullptr, nullptr, nullptr, r0, t); // Y
        __syncthreads();
        // LayerNorm rows in LDS: wave w handles rows 4w..4w+3
        for (int rr = 0; rr < 4; ++rr) {
            const int row = wave*4 + rr;
            float x[4];
            #pragma unroll
            for (int i = 0; i < 4; ++i) x[i] = b2f(sm.bufA[row][lane + 64*i]);
            float s = x[0]+x[1]+x[2]+x[3];
            float q = x[0]*x[0]+x[1]*x[1]+x[2]*x[2]+x[3]*x[3];
            #pragma unroll
            for (int off = 32; off; off >>= 1) {
                s += __shfl_down(s, off, 64);
                q += __shfl_down(q, off, 64);
            }
            s = __shfl(s, 0, 64); q = __shfl(q, 0, 64);
            const float mn  = s * (1.f/DM);
            const float vr  = q * (1.f/DM) - mn*mn;
            const float inv = rsqrtf(vr + 1e-5f);
            #pragma unroll
            for (int i = 0; i < 4; ++i) {
                const int c = lane + 64*i;
                sm.bufA[row][c] = f2b((x[i]-mn)*inv*g2[c] + be2[c]);
            }
        }
        // gemm3's leading __syncthreads covers the LN writes
        block_gemm256<2>(sm.bufA, W3T, nullptr, nullptr,
                         P, nullptr, nullptr, nullptr, r0, t);
        return;
    }

    {
        // ---------------- IoU row + exact top-k (block per row) -------------
        #pragma clang fp contract(off)
        // exact f32 — matches the numpy f32 reference bit-exactly on every
        // >=0.5 comparison, so attn_mask and top-k selection are exact.
        IouSmem& sm = *reinterpret_cast<IouSmem*>(smraw);
        const int row = bid - NTILE;         // b*NQ + i
        const int b   = row / NQ;
        if (t == 0) sm.scount = 0;

        const float* bi = boxes + (size_t)row * 4;
        const float icx = bi[0], icy = bi[1], iw = bi[2], ih = bi[3];
        const float ix0 = icx - 0.5f*iw, iy0 = icy - 0.5f*ih;
        const float ix1 = icx + 0.5f*iw, iy1 = icy + 0.5f*ih;
        const float area_i = (ix1-ix0)*(iy1-iy0);
        const float neg_i  = 1.f - seed[row];
        __syncthreads();

        float* arow = attn + (size_t)row * NQ;
        for (int j = t; j < NQ; j += 256) {
            const float* bj = boxes + (size_t)(b*NQ + j) * 4;
            const float cx = bj[0], cy = bj[1], w = bj[2], h = bj[3];
            const float x0 = cx - 0.5f*w, y0 = cy - 0.5f*h;
            const float x1 = cx + 0.5f*w, y1 = cy + 0.5f*h;
            const float area_j = (x1-x0)*(y1-y0);
            const float ltx = fmaxf(ix0, x0), lty = fmaxf(iy0, y0);
            const float rbx = fminf(ix1, x1), rby = fminf(iy1, y1);
            const float wx = fmaxf(rbx-ltx, 0.f), wy = fmaxf(rby-lty, 0.f);
            const float inter = wx*wy;
            const float uni = (area_i + area_j) - inter;
            const float iou = inter / uni;
            arow[j] = (iou >= 0.5f) ? 1.0f : 0.0f;
            const float ov = (iou * seed[b*NQ + j]) * neg_i;  // exact: seed,neg in {0,1}
            if (ov >= 0.5f) {
                const int p = atomicAdd(&sm.scount, 1);
                if (p < NQ) { sm.sv[p] = ov; sm.sj[p] = j; }
            }
        }
        __syncthreads();

        if (t == 0) {
            const int n = sm.scount;
            inc0[row] = (n < TOPK) ? 1 : 0;
            if (n <= TOPK) {
                cnt[row] = n;
                for (int k = 0; k < n; ++k) idxs[row*TOPK + k] = b*NQ + sm.sj[k];
            } else {
                // exact top-10 under (value desc, index asc) == stable argsort
                float bv[TOPK]; int bj[TOPK];
                #pragma unroll
                for (int k = 0; k < TOPK; ++k) { bv[k] = -1.f; bj[k] = 0x7fffffff; }
                for (int e = 0; e < n; ++e) {
                    const float v = sm.sv[e]; const int j = sm.sj[e];
                    int w = 0;
                    #pragma unroll
                    for (int k = 1; k < TOPK; ++k)
                        if (bv[k] < bv[w] || (bv[k] == bv[w] && bj[k] > bj[w])) w = k;
                    if (v > bv[w] || (v == bv[w] && j < bj[w])) { bv[w] = v; bj[w] = j; }
                }
                cnt[row] = TOPK;
                for (int k = 0; k < TOPK; ++k) idxs[row*TOPK + k] = b*NQ + bj[k];
            }
        }
    }
}

// ============ K3: pairs (MFMA + atomicMax fold) + final GEMM + residual ======
// W4/W5 B-fragments also read directly from global (same exactly-once
// argument): LDS drops 63.7 -> 26.8 KB (2 -> 4 blocks/CU), 2 barriers/chunk.
__global__ __launch_bounds__(256, 4) void pairs_final_k(
    const u16* __restrict__ P, const u16* __restrict__ WT,
    const float* __restrict__ b3, const float* __restrict__ b4,
    const float* __restrict__ b5,
    const int* __restrict__ cnt, const int* __restrict__ inc0,
    const int* __restrict__ idxs,
    const float* __restrict__ tgt, const float* __restrict__ seed,
    float* __restrict__ out)
{
    __shared__ __align__(16) u16 U[16][264];
    __shared__ u32 cmU[16][264];
    __shared__ int pl_rl[176], pl_j[176];
    __shared__ int sInc[16];
    __shared__ int np;
    const int t = threadIdx.x, r0 = blockIdx.x * 16;
    const int lane = t & 63, wave = t >> 6;
    const int m = lane & 15, quad = lane >> 4;
    const u16* W4T = WT + (size_t)3*DM*DM;
    const u16* W5T = WT + (size_t)4*DM*DM;

    if (t == 0) np = 0;
    __syncthreads();
    if (t < 16) {
        const int r = r0 + t;
        int c = cnt[r];
        c = (c < 0) ? 0 : ((c > TOPK) ? TOPK : c);
        sInc[t] = inc0[r];
        const int base = atomicAdd(&np, c);
        for (int k = 0; k < c; ++k) {
            pl_rl[base + k] = t;
            int j = idxs[r*TOPK + k];
            j = (j < 0) ? 0 : ((j >= MROWS) ? MROWS-1 : j);
            pl_j[base + k] = j;
        }
    }
    __syncthreads();
    const int npairs = np;
    #pragma unroll
    for (int rl2 = 0; rl2 < 16; ++rl2)
        cmU[rl2][t] = sInc[rl2] ? 0x80000000u /*encf(0)*/ : encf(-3.402823466e38f);
    const float bb3 = b3[t];
    const u16* W4b = W4T + (size_t)(wave*64 + m)*DM + quad*8;

    for (int pc = 0; pc*16 < npairs; ++pc) {
        // build U chunk (col t owned by thread t)
        #pragma unroll
        for (int pp = 0; pp < 16; ++pp) {
            const int pr = pc*16 + pp;
            u16 uv = 0;
            if (pr < npairs) {
                const int i = r0 + pl_rl[pr];
                const int j = pl_j[pr];
                uv = f2b(fmaxf(b2f(P[(size_t)i*DM + t]) - b2f(P[(size_t)j*DM + t]) + bb3, 0.f));
            }
            U[pp][t] = uv;
        }
        __syncthreads();   // U built (and cmU init visible before first folds)
        f32x4 acc[4];
        #pragma unroll
        for (int nt = 0; nt < 4; ++nt)
            #pragma unroll
            for (int i = 0; i < 4; ++i) acc[nt][i] = 0.f;
        for (int kc = 0; kc < 4; ++kc) {
            #pragma unroll
            for (int ks = 0; ks < 2; ++ks) {
                const short8 a = *(const short8*)&U[m][kc*64 + ks*32 + quad*8];
                #pragma unroll
                for (int nt = 0; nt < 4; ++nt) {
                    const short8 b = *(const short8*)&W4b[(size_t)nt*16*DM + kc*64 + ks*32];
                    acc[nt] = __builtin_amdgcn_mfma_f32_16x16x32_bf16(a, b, acc[nt], 0, 0, 0);
                }
            }
        }
        // fold D (row = quad*4+reg = pair slot, col = n) from registers
        #pragma unroll
        for (int nt = 0; nt < 4; ++nt) {
            const int n = wave*64 + nt*16 + m;
            const float bb4 = b4[n];
            #pragma unroll
            for (int reg = 0; reg < 4; ++reg) {
                const int pr = pc*16 + quad*4 + reg;
                if (pr < npairs) {
                    const int rl2 = pl_rl[pr];
                    atomicMax(&cmU[rl2][n], encf(acc[nt][reg] + bb4));
                }
            }
        }
        __syncthreads();   // all U reads done before next chunk's U build
    }
    __syncthreads();   // all folds complete before cross-thread cmU reads
    // CMAX -> bf16 A-tile (col t owned); gemm's leading sync orders it
    #pragma unroll
    for (int rl2 = 0; rl2 < 16; ++rl2)
        U[rl2][t] = f2b(decf(cmU[rl2][t]));
    block_gemm256<3>(U, W5T, b5, nullptr, nullptr, out,
                     tgt, seed, r0, t);
}

extern "C" void kernel_launch(void* const* d_in, const int* in_sizes, int n_in,
                              void* d_out, int out_size, void* d_ws, size_t ws_size,
                              hipStream_t stream)
{
    (void)in_sizes; (void)n_in; (void)out_size; (void)ws_size;
    const float* tgt   = (const float*)d_in[0];
    const float* seed  = (const float*)d_in[1];
    const float* boxes = (const float*)d_in[2];
    const float* W1 = (const float*)d_in[3];
    const float* b1 = (const float*)d_in[4];
    const float* W2 = (const float*)d_in[5];
    const float* b2 = (const float*)d_in[6];
    const float* g2 = (const float*)d_in[7];
    const float* be2= (const float*)d_in[8];
    const float* W3 = (const float*)d_in[9];
    const float* b3 = (const float*)d_in[10];
    const float* W4 = (const float*)d_in[11];
    const float* b4 = (const float*)d_in[12];
    const float* W5 = (const float*)d_in[13];
    const float* b5 = (const float*)d_in[14];

    float* out_tgt  = (float*)d_out;                     // 8*1000*256 f32
    float* out_attn = out_tgt + (size_t)MROWS * DM;      // 8*1000*1000 f32

    // ws: WT (5 x 128KB bf16) | P (4MB bf16) | meta (~0.36MB)  ~= 5.1 MB
    u16* WT   = (u16*)d_ws;
    u16* P    = WT + (size_t)5*DM*DM;
    int* cnt  = (int*)(P + (size_t)MROWS*DM);
    int* inc0 = cnt + MROWS;
    int* idxs = inc0 + MROWS;

    prep_k<<<80, 256, 0, stream>>>(W1, W2, W3, W4, W5, WT);
    fused_iou_mlp_k<<<NTILE + MROWS, 256, 0, stream>>>(
        boxes, seed, WT, b1, b2, g2, be2, tgt, P, out_attn, cnt, inc0, idxs);
    pairs_final_k<<<MROWS/16, 256, 0, stream>>>(P, WT, b3, b4, b5, cnt, inc0, idxs,
                                                tgt, seed, out_tgt);
}

// Round 6
// 143.868 us; speedup vs baseline: 1.1471x; 1.1471x over previous
//
#include <hip/hip_runtime.h>
#include <hip/hip_bf16.h>

#define BSZ   8
#define NQ    1000
#define DM    256
#define MROWS (BSZ*NQ)
#define TOPK  10
#define NTILE (MROWS/16)    // 500 MLP tiles
#define WSZ   (DM*DM)       // 65536 u16 per weight matrix

typedef __attribute__((ext_vector_type(8))) short short8;
typedef __attribute__((ext_vector_type(4))) float f32x4;
typedef unsigned short u16;
typedef unsigned int   u32;

static __device__ __forceinline__ float b2f(u16 u) { return __uint_as_float(((u32)u) << 16); }
static __device__ __forceinline__ u16 f2b(float f) {
    __hip_bfloat16 h = __float2bfloat16(f);   // RNE
    return *(u16*)&h;
}
// monotonic order-preserving float<->uint encoding (for atomicMax-based fmax)
static __device__ __forceinline__ u32 encf(float f) {
    u32 u = __float_as_uint(f);
    return (u & 0x80000000u) ? ~u : (u | 0x80000000u);
}
static __device__ __forceinline__ float decf(u32 e) {
    u32 u = (e & 0x80000000u) ? (e ^ 0x80000000u) : ~e;
    return __uint_as_float(u);
}

// ============ K0: weight prep — f32 W[k][n] -> FRAGMENT-LINEAR bf16 ==========
// Layout: WL[mi][wave][kc][ks][nt][lane][8], i.e. u16 offset
//   mi*65536 + wave*16384 + kc*4096 + ks*2048 + nt*512 + lane*8
// holding W[kc*64+ks*32+(lane>>4)*8+e][wave*64+nt*16+(lane&15)].
// This is exactly the MFMA B-fragment consumption order, so the GEMM's
// per-(kc,ks,nt) wave load is lane-contiguous (1KB/instr, fully coalesced)
// with NO LDS staging and NO barriers. (R5 lesson: direct loads from the
// [n][k] layout were 16-line scatter per instr -> latency-bound.)
// 80 blocks: mi(5) x wave(4) x kc(4).
__global__ __launch_bounds__(256) void prep_k(
    const float* __restrict__ W1, const float* __restrict__ W2,
    const float* __restrict__ W3, const float* __restrict__ W4,
    const float* __restrict__ W5, u16* __restrict__ WT)
{
    const int blk = blockIdx.x;
    const int mi = blk >> 4, w = (blk >> 2) & 3, kc = blk & 3;
    const float* W = (mi==0)?W1:(mi==1)?W2:(mi==2)?W3:(mi==3)?W4:W5;
    u16* D = WT + (size_t)mi*WSZ + w*16384 + kc*4096;
    const int t = threadIdx.x, lane = t & 63, half = t >> 6;
    const int m = lane & 15, quad = lane >> 4;
    #pragma unroll
    for (int gi = 0; gi < 2; ++gi) {
        const int g  = half + gi*4;          // 0..7
        const int ks = g >> 2, nt = g & 3;
        const int kbase = kc*64 + ks*32 + quad*8;
        const int n     = w*64 + nt*16 + m;
        __align__(16) u16 tmp[8];
        #pragma unroll
        for (int e = 0; e < 8; ++e)
            tmp[e] = f2b(W[(size_t)(kbase+e)*DM + n]);
        *(uint4*)&D[ks*2048 + nt*512 + lane*8] = *(const uint4*)&tmp[0];
    }
}

// ============ shared 16x256x256 block-GEMM (MFMA 16x16x32 bf16) ==============
// A is a [16][264] bf16 LDS tile; WF is the fragment-linear weight (above).
// Single barrier per GEMM; B streams straight from L2 into MFMA operands.
// MFMA order (kc->ks->nt) identical to all prior rounds => bit-identical.
// Epilogue variants:
//   0: relu(acc+bias) -> OutL    1: acc+bias -> OutL
//   2: acc -> OutG (bf16 global) 3: final residual -> OutF (f32 global)
template<int EPI>
static __device__ __forceinline__ void block_gemm256(
    const u16 (*__restrict__ A)[264], const u16* __restrict__ WF,
    const float* __restrict__ bias, u16 (*__restrict__ OutL)[264],
    u16* __restrict__ OutG, float* __restrict__ OutF,
    const float* __restrict__ tgt, const float* __restrict__ seed,
    int r0, int t)
{
    const int lane = t & 63, wave = t >> 6;
    const int m = lane & 15, quad = lane >> 4;
    f32x4 acc[4];
    #pragma unroll
    for (int nt = 0; nt < 4; ++nt)
        #pragma unroll
        for (int i = 0; i < 4; ++i) acc[nt][i] = 0.f;
    __syncthreads();   // A tile ready (and prior users of the A buffer done)
    const u16* Wb = WF + (size_t)wave*16384 + lane*8;
    #pragma unroll
    for (int kc = 0; kc < 4; ++kc) {
        #pragma unroll
        for (int ks = 0; ks < 2; ++ks) {
            const short8 a = *(const short8*)&A[m][kc*64 + ks*32 + quad*8];
            #pragma unroll
            for (int nt = 0; nt < 4; ++nt) {
                const short8 b = *(const short8*)&Wb[kc*4096 + ks*2048 + nt*512];
                acc[nt] = __builtin_amdgcn_mfma_f32_16x16x32_bf16(a, b, acc[nt], 0, 0, 0);
            }
        }
    }
    // C/D: row = quad*4+reg, col = wave*64+nt*16+m  (verified R4/R5)
    #pragma unroll
    for (int nt = 0; nt < 4; ++nt) {
        const int n = wave*64 + nt*16 + m;
        const float bb = bias ? bias[n] : 0.f;
        #pragma unroll
        for (int reg = 0; reg < 4; ++reg) {
            const int rl = quad*4 + reg;
            float v = acc[nt][reg] + bb;
            if (EPI == 0) OutL[rl][n] = f2b(fmaxf(v, 0.f));
            if (EPI == 1) OutL[rl][n] = f2b(v);
            if (EPI == 2) OutG[(size_t)(r0+rl)*DM + n] = f2b(v);
            if (EPI == 3) {
                const int R = r0 + rl;
                OutF[(size_t)R*DM + n] = tgt[(size_t)R*DM + n]
                                       + fmaxf(v, 0.f) * (1.f - seed[R]);
            }
        }
    }
}

// LDS overlay: MLP tiles need 16.9KB (bufA+bufB); IoU rows 8KB.
struct MlpSmem { u16 bufA[16][264]; u16 bufB[16][264]; };
struct IouSmem { float sv[NQ]; int sj[NQ]; int scount; };

// ============ K12: fused MLP chain (blocks 0..499) + IoU rows (500..8499) ====
__global__ __launch_bounds__(256, 4) void fused_iou_mlp_k(
    const float* __restrict__ boxes, const float* __restrict__ seed,
    const u16* __restrict__ WT,
    const float* __restrict__ b1, const float* __restrict__ b2,
    const float* __restrict__ g2, const float* __restrict__ be2,
    const float* __restrict__ tgt,
    u16* __restrict__ P, float* __restrict__ attn,
    int* __restrict__ cnt, int* __restrict__ inc0, int* __restrict__ idxs)
{
    __shared__ __align__(16) unsigned char smraw[sizeof(MlpSmem)];
    const int t = threadIdx.x;
    const int bid = blockIdx.x;

    if (bid < NTILE) {
        // ---------------- MLP tile: tgt -> H -> Y -> LN -> P ----------------
        MlpSmem& sm = *reinterpret_cast<MlpSmem*>(smraw);
        const int r0 = bid * 16;
        const int lane = t & 63, wave = t >> 6;
        const u16* W1F = WT;
        const u16* W2F = WT + (size_t)1*WSZ;
        const u16* W3F = WT + (size_t)2*WSZ;

        // stage tgt f32 -> bufA bf16 (thread t: row t>>4, 16 cols from (t&15)*16)
        {
            const int r = t >> 4, c0 = (t & 15) * 16;
            const float* src = &tgt[(size_t)(r0 + r)*DM + c0];
            __align__(16) u16 h[16];
            #pragma unroll
            for (int q = 0; q < 4; ++q) {
                const float4 f = *(const float4*)&src[q*4];
                h[q*4+0] = f2b(f.x); h[q*4+1] = f2b(f.y);
                h[q*4+2] = f2b(f.z); h[q*4+3] = f2b(f.w);
            }
            *(uint4*)&sm.bufA[r][c0]     = *(uint4*)&h[0];
            *(uint4*)&sm.bufA[r][c0 + 8] = *(uint4*)&h[8];
        }

        block_gemm256<0>(sm.bufA, W1F, b1, sm.bufB,
                         nullptr, nullptr, nullptr, nullptr, r0, t); // H
        block_gemm256<1>(sm.bufB, W2F, b2, sm.bufA,
                         nullptr, nullptr, nullptr, nullptr, r0, t); // Y
        __syncthreads();
        // LayerNorm rows in LDS: wave w handles rows 4w..4w+3
        for (int rr = 0; rr < 4; ++rr) {
            const int row = wave*4 + rr;
            float x[4];
            #pragma unroll
            for (int i = 0; i < 4; ++i) x[i] = b2f(sm.bufA[row][lane + 64*i]);
            float s = x[0]+x[1]+x[2]+x[3];
            float q = x[0]*x[0]+x[1]*x[1]+x[2]*x[2]+x[3]*x[3];
            #pragma unroll
            for (int off = 32; off; off >>= 1) {
                s += __shfl_down(s, off, 64);
                q += __shfl_down(q, off, 64);
            }
            s = __shfl(s, 0, 64); q = __shfl(q, 0, 64);
            const float mn  = s * (1.f/DM);
            const float vr  = q * (1.f/DM) - mn*mn;
            const float inv = rsqrtf(vr + 1e-5f);
            #pragma unroll
            for (int i = 0; i < 4; ++i) {
                const int c = lane + 64*i;
                sm.bufA[row][c] = f2b((x[i]-mn)*inv*g2[c] + be2[c]);
            }
        }
        // gemm3's leading __syncthreads covers the LN writes
        block_gemm256<2>(sm.bufA, W3F, nullptr, nullptr,
                         P, nullptr, nullptr, nullptr, r0, t);
        return;
    }

    {
        // ---------------- IoU row + exact top-k (block per row) -------------
        #pragma clang fp contract(off)
        // exact f32 — matches the numpy f32 reference bit-exactly on every
        // >=0.5 comparison, so attn_mask and top-k selection are exact.
        IouSmem& sm = *reinterpret_cast<IouSmem*>(smraw);
        const int row = bid - NTILE;         // b*NQ + i
        const int b   = row / NQ;
        if (t == 0) sm.scount = 0;

        const float* bi = boxes + (size_t)row * 4;
        const float icx = bi[0], icy = bi[1], iw = bi[2], ih = bi[3];
        const float ix0 = icx - 0.5f*iw, iy0 = icy - 0.5f*ih;
        const float ix1 = icx + 0.5f*iw, iy1 = icy + 0.5f*ih;
        const float area_i = (ix1-ix0)*(iy1-iy0);
        const float neg_i  = 1.f - seed[row];
        __syncthreads();

        float* arow = attn + (size_t)row * NQ;
        for (int j = t; j < NQ; j += 256) {
            const float* bj = boxes + (size_t)(b*NQ + j) * 4;
            const float cx = bj[0], cy = bj[1], w = bj[2], h = bj[3];
            const float x0 = cx - 0.5f*w, y0 = cy - 0.5f*h;
            const float x1 = cx + 0.5f*w, y1 = cy + 0.5f*h;
            const float area_j = (x1-x0)*(y1-y0);
            const float ltx = fmaxf(ix0, x0), lty = fmaxf(iy0, y0);
            const float rbx = fminf(ix1, x1), rby = fminf(iy1, y1);
            const float wx = fmaxf(rbx-ltx, 0.f), wy = fmaxf(rby-lty, 0.f);
            const float inter = wx*wy;
            const float uni = (area_i + area_j) - inter;
            const float iou = inter / uni;
            arow[j] = (iou >= 0.5f) ? 1.0f : 0.0f;
            const float ov = (iou * seed[b*NQ + j]) * neg_i;  // exact: seed,neg in {0,1}
            if (ov >= 0.5f) {
                const int p = atomicAdd(&sm.scount, 1);
                if (p < NQ) { sm.sv[p] = ov; sm.sj[p] = j; }
            }
        }
        __syncthreads();

        if (t == 0) {
            const int n = sm.scount;
            inc0[row] = (n < TOPK) ? 1 : 0;
            if (n <= TOPK) {
                cnt[row] = n;
                for (int k = 0; k < n; ++k) idxs[row*TOPK + k] = b*NQ + sm.sj[k];
            } else {
                // exact top-10 under (value desc, index asc) == stable argsort
                float bv[TOPK]; int bj[TOPK];
                #pragma unroll
                for (int k = 0; k < TOPK; ++k) { bv[k] = -1.f; bj[k] = 0x7fffffff; }
                for (int e = 0; e < n; ++e) {
                    const float v = sm.sv[e]; const int j = sm.sj[e];
                    int w = 0;
                    #pragma unroll
                    for (int k = 1; k < TOPK; ++k)
                        if (bv[k] < bv[w] || (bv[k] == bv[w] && bj[k] > bj[w])) w = k;
                    if (v > bv[w] || (v == bv[w] && j < bj[w])) { bv[w] = v; bj[w] = j; }
                }
                cnt[row] = TOPK;
                for (int k = 0; k < TOPK; ++k) idxs[row*TOPK + k] = b*NQ + bj[k];
            }
        }
    }
}

// ============ K3: pairs (MFMA + atomicMax fold) + final GEMM + residual ======
// W4/W5 fragments stream from the fragment-linear layout (coalesced, no LDS).
// The W4 fragment addresses are pc-invariant -> compiler hoists a subset into
// registers across chunks. LDS 26.8KB -> ~5 blocks/CU.
__global__ __launch_bounds__(256, 4) void pairs_final_k(
    const u16* __restrict__ P, const u16* __restrict__ WT,
    const float* __restrict__ b3, const float* __restrict__ b4,
    const float* __restrict__ b5,
    const int* __restrict__ cnt, const int* __restrict__ inc0,
    const int* __restrict__ idxs,
    const float* __restrict__ tgt, const float* __restrict__ seed,
    float* __restrict__ out)
{
    __shared__ __align__(16) u16 U[16][264];
    __shared__ u32 cmU[16][264];
    __shared__ int pl_rl[176], pl_j[176];
    __shared__ int sInc[16];
    __shared__ int np;
    const int t = threadIdx.x, r0 = blockIdx.x * 16;
    const int lane = t & 63, wave = t >> 6;
    const int m = lane & 15, quad = lane >> 4;
    const u16* W4F = WT + (size_t)3*WSZ;
    const u16* W5F = WT + (size_t)4*WSZ;

    if (t == 0) np = 0;
    __syncthreads();
    if (t < 16) {
        const int r = r0 + t;
        int c = cnt[r];
        c = (c < 0) ? 0 : ((c > TOPK) ? TOPK : c);
        sInc[t] = inc0[r];
        const int base = atomicAdd(&np, c);
        for (int k = 0; k < c; ++k) {
            pl_rl[base + k] = t;
            int j = idxs[r*TOPK + k];
            j = (j < 0) ? 0 : ((j >= MROWS) ? MROWS-1 : j);
            pl_j[base + k] = j;
        }
    }
    __syncthreads();
    const int npairs = np;
    #pragma unroll
    for (int rl2 = 0; rl2 < 16; ++rl2)
        cmU[rl2][t] = sInc[rl2] ? 0x80000000u /*encf(0)*/ : encf(-3.402823466e38f);
    const float bb3 = b3[t];
    const u16* W4b = W4F + (size_t)wave*16384 + lane*8;

    for (int pc = 0; pc*16 < npairs; ++pc) {
        // build U chunk (col t owned by thread t)
        #pragma unroll
        for (int pp = 0; pp < 16; ++pp) {
            const int pr = pc*16 + pp;
            u16 uv = 0;
            if (pr < npairs) {
                const int i = r0 + pl_rl[pr];
                const int j = pl_j[pr];
                uv = f2b(fmaxf(b2f(P[(size_t)i*DM + t]) - b2f(P[(size_t)j*DM + t]) + bb3, 0.f));
            }
            U[pp][t] = uv;
        }
        __syncthreads();   // U built (and cmU init visible before first folds)
        f32x4 acc[4];
        #pragma unroll
        for (int nt = 0; nt < 4; ++nt)
            #pragma unroll
            for (int i = 0; i < 4; ++i) acc[nt][i] = 0.f;
        #pragma unroll
        for (int kc = 0; kc < 4; ++kc) {
            #pragma unroll
            for (int ks = 0; ks < 2; ++ks) {
                const short8 a = *(const short8*)&U[m][kc*64 + ks*32 + quad*8];
                #pragma unroll
                for (int nt = 0; nt < 4; ++nt) {
                    const short8 b = *(const short8*)&W4b[kc*4096 + ks*2048 + nt*512];
                    acc[nt] = __builtin_amdgcn_mfma_f32_16x16x32_bf16(a, b, acc[nt], 0, 0, 0);
                }
            }
        }
        // fold D (row = quad*4+reg = pair slot, col = n) from registers
        #pragma unroll
        for (int nt = 0; nt < 4; ++nt) {
            const int n = wave*64 + nt*16 + m;
            const float bb4 = b4[n];
            #pragma unroll
            for (int reg = 0; reg < 4; ++reg) {
                const int pr = pc*16 + quad*4 + reg;
                if (pr < npairs) {
                    const int rl2 = pl_rl[pr];
                    atomicMax(&cmU[rl2][n], encf(acc[nt][reg] + bb4));
                }
            }
        }
        __syncthreads();   // all U reads done before next chunk's U build
    }
    __syncthreads();   // all folds complete before cross-thread cmU reads
    // CMAX -> bf16 A-tile (col t owned); gemm's leading sync orders it
    #pragma unroll
    for (int rl2 = 0; rl2 < 16; ++rl2)
        U[rl2][t] = f2b(decf(cmU[rl2][t]));
    block_gemm256<3>(U, W5F, b5, nullptr, nullptr, out,
                     tgt, seed, r0, t);
}

extern "C" void kernel_launch(void* const* d_in, const int* in_sizes, int n_in,
                              void* d_out, int out_size, void* d_ws, size_t ws_size,
                              hipStream_t stream)
{
    (void)in_sizes; (void)n_in; (void)out_size; (void)ws_size;
    const float* tgt   = (const float*)d_in[0];
    const float* seed  = (const float*)d_in[1];
    const float* boxes = (const float*)d_in[2];
    const float* W1 = (const float*)d_in[3];
    const float* b1 = (const float*)d_in[4];
    const float* W2 = (const float*)d_in[5];
    const float* b2 = (const float*)d_in[6];
    const float* g2 = (const float*)d_in[7];
    const float* be2= (const float*)d_in[8];
    const float* W3 = (const float*)d_in[9];
    const float* b3 = (const float*)d_in[10];
    const float* W4 = (const float*)d_in[11];
    const float* b4 = (const float*)d_in[12];
    const float* W5 = (const float*)d_in[13];
    const float* b5 = (const float*)d_in[14];

    float* out_tgt  = (float*)d_out;                     // 8*1000*256 f32
    float* out_attn = out_tgt + (size_t)MROWS * DM;      // 8*1000*1000 f32

    // ws: WT (5 x 128KB bf16, fragment-linear) | P (4MB bf16) | meta ~= 5.1 MB
    u16* WT   = (u16*)d_ws;
    u16* P    = WT + (size_t)5*WSZ;
    int* cnt  = (int*)(P + (size_t)MROWS*DM);
    int* inc0 = cnt + MROWS;
    int* idxs = inc0 + MROWS;

    prep_k<<<80, 256, 0, stream>>>(W1, W2, W3, W4, W5, WT);
    fused_iou_mlp_k<<<NTILE + MROWS, 256, 0, stream>>>(
        boxes, seed, WT, b1, b2, g2, be2, tgt, P, out_attn, cnt, inc0, idxs);
    pairs_final_k<<<MROWS/16, 256, 0, stream>>>(P, WT, b3, b4, b5, cnt, inc0, idxs,
                                                tgt, seed, out_tgt);
}

// Round 7
// 139.219 us; speedup vs baseline: 1.1854x; 1.0334x over previous
//
#include <hip/hip_runtime.h>
#include <hip/hip_bf16.h>

#define BSZ   8
#define NQ    1000
#define DM    256
#define MROWS (BSZ*NQ)
#define TOPK  10
#define NTILE (MROWS/16)    // 500 MLP tiles
#define WSZ   (DM*DM)       // 65536 u16 per weight matrix

typedef __attribute__((ext_vector_type(8))) short short8;
typedef __attribute__((ext_vector_type(4))) float f32x4;
typedef unsigned short u16;
typedef unsigned int   u32;

static __device__ __forceinline__ float b2f(u16 u) { return __uint_as_float(((u32)u) << 16); }
static __device__ __forceinline__ u16 f2b(float f) {
    __hip_bfloat16 h = __float2bfloat16(f);   // RNE
    return *(u16*)&h;
}
// monotonic order-preserving float<->uint encoding (for atomicMax-based fmax)
static __device__ __forceinline__ u32 encf(float f) {
    u32 u = __float_as_uint(f);
    return (u & 0x80000000u) ? ~u : (u | 0x80000000u);
}
static __device__ __forceinline__ float decf(u32 e) {
    u32 u = (e & 0x80000000u) ? (e ^ 0x80000000u) : ~e;
    return __uint_as_float(u);
}

// ============ K0: prep — weights -> fragment-linear bf16; boxes -> xyxy+area =
// Blocks 0..79: weight prep (mi x wave x kc), layout
//   WL[mi][wave][kc][ks][nt][lane][8]  (MFMA B-fragment consumption order;
//   per-(kc,ks,nt) wave load is lane-contiguous -> 1KB/instr coalesced).
// Blocks 80..111: box transform cxcywh -> (x0,y0,x1,y1) float4 + area,
//   exact same op order as the reference (contract off) => bit-identical IoU.
__global__ __launch_bounds__(256) void prep_k(
    const float* __restrict__ W1, const float* __restrict__ W2,
    const float* __restrict__ W3, const float* __restrict__ W4,
    const float* __restrict__ W5, const float* __restrict__ boxes,
    u16* __restrict__ WT, float4* __restrict__ bx4, float* __restrict__ bar)
{
    const int blk = blockIdx.x;
    const int t = threadIdx.x;
    if (blk < 80) {
        const int mi = blk >> 4, w = (blk >> 2) & 3, kc = blk & 3;
        const float* W = (mi==0)?W1:(mi==1)?W2:(mi==2)?W3:(mi==3)?W4:W5;
        u16* D = WT + (size_t)mi*WSZ + w*16384 + kc*4096;
        const int lane = t & 63, half = t >> 6;
        const int m = lane & 15, quad = lane >> 4;
        #pragma unroll
        for (int gi = 0; gi < 2; ++gi) {
            const int g  = half + gi*4;          // 0..7
            const int ks = g >> 2, nt = g & 3;
            const int kbase = kc*64 + ks*32 + quad*8;
            const int n     = w*64 + nt*16 + m;
            __align__(16) u16 tmp[8];
            #pragma unroll
            for (int e = 0; e < 8; ++e)
                tmp[e] = f2b(W[(size_t)(kbase+e)*DM + n]);
            *(uint4*)&D[ks*2048 + nt*512 + lane*8] = *(const uint4*)&tmp[0];
        }
        return;
    }
    {
        #pragma clang fp contract(off)
        const int idx = (blk - 80)*256 + t;
        if (idx < MROWS) {
            const float4 bb = *(const float4*)&boxes[(size_t)idx*4];
            const float x0 = bb.x - 0.5f*bb.z, y0 = bb.y - 0.5f*bb.w;
            const float x1 = bb.x + 0.5f*bb.z, y1 = bb.y + 0.5f*bb.w;
            bx4[idx] = make_float4(x0, y0, x1, y1);
            bar[idx] = (x1-x0)*(y1-y0);
        }
    }
}

// ============ shared 16x256x256 block-GEMM (MFMA 16x16x32 bf16) ==============
// A is a [16][264] bf16 LDS tile; WF is the fragment-linear weight (above).
// Single barrier per GEMM; B streams straight from L2 into MFMA operands.
// MFMA order (kc->ks->nt) identical to all prior rounds => bit-identical.
// Epilogue variants:
//   0: relu(acc+bias) -> OutL    1: acc+bias -> OutL
//   2: acc -> OutG (bf16 global) 3: final residual -> OutF (f32 global)
template<int EPI>
static __device__ __forceinline__ void block_gemm256(
    const u16 (*__restrict__ A)[264], const u16* __restrict__ WF,
    const float* __restrict__ bias, u16 (*__restrict__ OutL)[264],
    u16* __restrict__ OutG, float* __restrict__ OutF,
    const float* __restrict__ tgt, const float* __restrict__ seed,
    int r0, int t)
{
    const int lane = t & 63, wave = t >> 6;
    const int m = lane & 15, quad = lane >> 4;
    f32x4 acc[4];
    #pragma unroll
    for (int nt = 0; nt < 4; ++nt)
        #pragma unroll
        for (int i = 0; i < 4; ++i) acc[nt][i] = 0.f;
    __syncthreads();   // A tile ready (and prior users of the A buffer done)
    const u16* Wb = WF + (size_t)wave*16384 + lane*8;
    #pragma unroll
    for (int kc = 0; kc < 4; ++kc) {
        #pragma unroll
        for (int ks = 0; ks < 2; ++ks) {
            const short8 a = *(const short8*)&A[m][kc*64 + ks*32 + quad*8];
            #pragma unroll
            for (int nt = 0; nt < 4; ++nt) {
                const short8 b = *(const short8*)&Wb[kc*4096 + ks*2048 + nt*512];
                acc[nt] = __builtin_amdgcn_mfma_f32_16x16x32_bf16(a, b, acc[nt], 0, 0, 0);
            }
        }
    }
    // C/D: row = quad*4+reg, col = wave*64+nt*16+m  (verified R4/R5)
    #pragma unroll
    for (int nt = 0; nt < 4; ++nt) {
        const int n = wave*64 + nt*16 + m;
        const float bb = bias ? bias[n] : 0.f;
        #pragma unroll
        for (int reg = 0; reg < 4; ++reg) {
            const int rl = quad*4 + reg;
            float v = acc[nt][reg] + bb;
            if (EPI == 0) OutL[rl][n] = f2b(fmaxf(v, 0.f));
            if (EPI == 1) OutL[rl][n] = f2b(v);
            if (EPI == 2) OutG[(size_t)(r0+rl)*DM + n] = f2b(v);
            if (EPI == 3) {
                const int R = r0 + rl;
                OutF[(size_t)R*DM + n] = tgt[(size_t)R*DM + n]
                                       + fmaxf(v, 0.f) * (1.f - seed[R]);
            }
        }
    }
}

// LDS overlay: MLP tiles 16.9KB (bufA+bufB); IoU 2-row blocks 16.0KB.
struct MlpSmem  { u16 bufA[16][264]; u16 bufB[16][264]; };
struct Iou2Smem { float sv[2][NQ]; int sj[2][NQ]; int scount[2]; };

// ============ K12: fused MLP chain (blocks 0..499) + IoU 2-row blocks ========
// IoU: 2 rows per block (rows 2p, 2p+1 — same batch since NQ is even). Both
// rows share every bj/area/seed load -> per-block latency ~unchanged, block
// count halved (8000 -> 4000). Boxes come pre-transformed from prep_k.
__global__ __launch_bounds__(256, 4) void fused_iou_mlp_k(
    const float4* __restrict__ bx4, const float* __restrict__ bar,
    const float* __restrict__ seed,
    const u16* __restrict__ WT,
    const float* __restrict__ b1, const float* __restrict__ b2,
    const float* __restrict__ g2, const float* __restrict__ be2,
    const float* __restrict__ tgt,
    u16* __restrict__ P, float* __restrict__ attn,
    int* __restrict__ cnt, int* __restrict__ inc0, int* __restrict__ idxs)
{
    __shared__ __align__(16) unsigned char smraw[sizeof(MlpSmem)];
    const int t = threadIdx.x;
    const int bid = blockIdx.x;

    if (bid < NTILE) {
        // ---------------- MLP tile: tgt -> H -> Y -> LN -> P ----------------
        MlpSmem& sm = *reinterpret_cast<MlpSmem*>(smraw);
        const int r0 = bid * 16;
        const int lane = t & 63, wave = t >> 6;
        const u16* W1F = WT;
        const u16* W2F = WT + (size_t)1*WSZ;
        const u16* W3F = WT + (size_t)2*WSZ;

        // stage tgt f32 -> bufA bf16 (thread t: row t>>4, 16 cols from (t&15)*16)
        {
            const int r = t >> 4, c0 = (t & 15) * 16;
            const float* src = &tgt[(size_t)(r0 + r)*DM + c0];
            __align__(16) u16 h[16];
            #pragma unroll
            for (int q = 0; q < 4; ++q) {
                const float4 f = *(const float4*)&src[q*4];
                h[q*4+0] = f2b(f.x); h[q*4+1] = f2b(f.y);
                h[q*4+2] = f2b(f.z); h[q*4+3] = f2b(f.w);
            }
            *(uint4*)&sm.bufA[r][c0]     = *(uint4*)&h[0];
            *(uint4*)&sm.bufA[r][c0 + 8] = *(uint4*)&h[8];
        }

        block_gemm256<0>(sm.bufA, W1F, b1, sm.bufB,
                         nullptr, nullptr, nullptr, nullptr, r0, t); // H
        block_gemm256<1>(sm.bufB, W2F, b2, sm.bufA,
                         nullptr, nullptr, nullptr, nullptr, r0, t); // Y
        __syncthreads();
        // LayerNorm rows in LDS: wave w handles rows 4w..4w+3
        for (int rr = 0; rr < 4; ++rr) {
            const int row = wave*4 + rr;
            float x[4];
            #pragma unroll
            for (int i = 0; i < 4; ++i) x[i] = b2f(sm.bufA[row][lane + 64*i]);
            float s = x[0]+x[1]+x[2]+x[3];
            float q = x[0]*x[0]+x[1]*x[1]+x[2]*x[2]+x[3]*x[3];
            #pragma unroll
            for (int off = 32; off; off >>= 1) {
                s += __shfl_down(s, off, 64);
                q += __shfl_down(q, off, 64);
            }
            s = __shfl(s, 0, 64); q = __shfl(q, 0, 64);
            const float mn  = s * (1.f/DM);
            const float vr  = q * (1.f/DM) - mn*mn;
            const float inv = rsqrtf(vr + 1e-5f);
            #pragma unroll
            for (int i = 0; i < 4; ++i) {
                const int c = lane + 64*i;
                sm.bufA[row][c] = f2b((x[i]-mn)*inv*g2[c] + be2[c]);
            }
        }
        // gemm3's leading __syncthreads covers the LN writes
        block_gemm256<2>(sm.bufA, W3F, nullptr, nullptr,
                         P, nullptr, nullptr, nullptr, r0, t);
        return;
    }

    {
        // ---------------- IoU 2 rows + exact top-k per row ------------------
        #pragma clang fp contract(off)
        // exact f32 — matches the numpy f32 reference bit-exactly on every
        // >=0.5 comparison, so attn_mask and top-k selection are exact.
        Iou2Smem& sm = *reinterpret_cast<Iou2Smem*>(smraw);
        const int pb   = bid - NTILE;        // 0..3999
        const int row0 = pb * 2;
        const int b    = row0 / NQ;          // rows 2p,2p+1 share the batch
        if (t < 2) sm.scount[t] = 0;

        const float4 b0 = bx4[row0];
        const float4 b1v = bx4[row0 + 1];
        const float a0 = bar[row0],            a1 = bar[row0 + 1];
        const float n0 = 1.f - seed[row0],     n1 = 1.f - seed[row0 + 1];
        __syncthreads();

        float* arow0 = attn + (size_t)row0 * NQ;
        float* arow1 = arow0 + NQ;
        const float4* bxb = bx4 + (size_t)b * NQ;
        const float*  bab = bar + (size_t)b * NQ;
        const float*  sdb = seed + (size_t)b * NQ;
        for (int j = t; j < NQ; j += 256) {
            const float4 bj = bxb[j];
            const float  aj = bab[j];
            const float  sd = sdb[j];
            // row 0
            {
                const float ltx = fmaxf(b0.x, bj.x), lty = fmaxf(b0.y, bj.y);
                const float rbx = fminf(b0.z, bj.z), rby = fminf(b0.w, bj.w);
                const float wx = fmaxf(rbx-ltx, 0.f), wy = fmaxf(rby-lty, 0.f);
                const float inter = wx*wy;
                const float uni = (a0 + aj) - inter;
                const float iou = inter / uni;
                arow0[j] = (iou >= 0.5f) ? 1.0f : 0.0f;
                const float ov = (iou * sd) * n0;
                if (ov >= 0.5f) {
                    const int p = atomicAdd(&sm.scount[0], 1);
                    if (p < NQ) { sm.sv[0][p] = ov; sm.sj[0][p] = j; }
                }
            }
            // row 1
            {
                const float ltx = fmaxf(b1v.x, bj.x), lty = fmaxf(b1v.y, bj.y);
                const float rbx = fminf(b1v.z, bj.z), rby = fminf(b1v.w, bj.w);
                const float wx = fmaxf(rbx-ltx, 0.f), wy = fmaxf(rby-lty, 0.f);
                const float inter = wx*wy;
                const float uni = (a1 + aj) - inter;
                const float iou = inter / uni;
                arow1[j] = (iou >= 0.5f) ? 1.0f : 0.0f;
                const float ov = (iou * sd) * n1;
                if (ov >= 0.5f) {
                    const int p = atomicAdd(&sm.scount[1], 1);
                    if (p < NQ) { sm.sv[1][p] = ov; sm.sj[1][p] = j; }
                }
            }
        }
        __syncthreads();

        if ((t & 63) == 0 && t < 128) {      // lane 0 of waves 0 and 1
            const int r   = t >> 6;          // 0 or 1
            const int row = row0 + r;
            const int n = sm.scount[r];
            inc0[row] = (n < TOPK) ? 1 : 0;
            if (n <= TOPK) {
                cnt[row] = n;
                for (int k = 0; k < n; ++k) idxs[row*TOPK + k] = b*NQ + sm.sj[r][k];
            } else {
                // exact top-10 under (value desc, index asc) == stable argsort
                float bv[TOPK]; int bj[TOPK];
                #pragma unroll
                for (int k = 0; k < TOPK; ++k) { bv[k] = -1.f; bj[k] = 0x7fffffff; }
                for (int e = 0; e < n; ++e) {
                    const float v = sm.sv[r][e]; const int j = sm.sj[r][e];
                    int w = 0;
                    #pragma unroll
                    for (int k = 1; k < TOPK; ++k)
                        if (bv[k] < bv[w] || (bv[k] == bv[w] && bj[k] > bj[w])) w = k;
                    if (v > bv[w] || (v == bv[w] && j < bj[w])) { bv[w] = v; bj[w] = j; }
                }
                cnt[row] = TOPK;
                for (int k = 0; k < TOPK; ++k) idxs[row*TOPK + k] = b*NQ + bj[k];
            }
        }
    }
}

// ============ K3: pairs (MFMA + atomicMax fold) + final GEMM + residual ======
// W4/W5 fragments stream from the fragment-linear layout (coalesced, no LDS).
__global__ __launch_bounds__(256, 4) void pairs_final_k(
    const u16* __restrict__ P, const u16* __restrict__ WT,
    const float* __restrict__ b3, const float* __restrict__ b4,
    const float* __restrict__ b5,
    const int* __restrict__ cnt, const int* __restrict__ inc0,
    const int* __restrict__ idxs,
    const float* __restrict__ tgt, const float* __restrict__ seed,
    float* __restrict__ out)
{
    __shared__ __align__(16) u16 U[16][264];
    __shared__ u32 cmU[16][264];
    __shared__ int pl_rl[176], pl_j[176];
    __shared__ int sInc[16];
    __shared__ int np;
    const int t = threadIdx.x, r0 = blockIdx.x * 16;
    const int lane = t & 63, wave = t >> 6;
    const int m = lane & 15, quad = lane >> 4;
    const u16* W4F = WT + (size_t)3*WSZ;
    const u16* W5F = WT + (size_t)4*WSZ;

    if (t == 0) np = 0;
    __syncthreads();
    if (t < 16) {
        const int r = r0 + t;
        int c = cnt[r];
        c = (c < 0) ? 0 : ((c > TOPK) ? TOPK : c);
        sInc[t] = inc0[r];
        const int base = atomicAdd(&np, c);
        for (int k = 0; k < c; ++k) {
            pl_rl[base + k] = t;
            int j = idxs[r*TOPK + k];
            j = (j < 0) ? 0 : ((j >= MROWS) ? MROWS-1 : j);
            pl_j[base + k] = j;
        }
    }
    __syncthreads();
    const int npairs = np;
    #pragma unroll
    for (int rl2 = 0; rl2 < 16; ++rl2)
        cmU[rl2][t] = sInc[rl2] ? 0x80000000u /*encf(0)*/ : encf(-3.402823466e38f);
    const float bb3 = b3[t];
    const u16* W4b = W4F + (size_t)wave*16384 + lane*8;

    for (int pc = 0; pc*16 < npairs; ++pc) {
        // build U chunk (col t owned by thread t)
        #pragma unroll
        for (int pp = 0; pp < 16; ++pp) {
            const int pr = pc*16 + pp;
            u16 uv = 0;
            if (pr < npairs) {
                const int i = r0 + pl_rl[pr];
                const int j = pl_j[pr];
                uv = f2b(fmaxf(b2f(P[(size_t)i*DM + t]) - b2f(P[(size_t)j*DM + t]) + bb3, 0.f));
            }
            U[pp][t] = uv;
        }
        __syncthreads();   // U built (and cmU init visible before first folds)
        f32x4 acc[4];
        #pragma unroll
        for (int nt = 0; nt < 4; ++nt)
            #pragma unroll
            for (int i = 0; i < 4; ++i) acc[nt][i] = 0.f;
        #pragma unroll
        for (int kc = 0; kc < 4; ++kc) {
            #pragma unroll
            for (int ks = 0; ks < 2; ++ks) {
                const short8 a = *(const short8*)&U[m][kc*64 + ks*32 + quad*8];
                #pragma unroll
                for (int nt = 0; nt < 4; ++nt) {
                    const short8 b = *(const short8*)&W4b[kc*4096 + ks*2048 + nt*512];
                    acc[nt] = __builtin_amdgcn_mfma_f32_16x16x32_bf16(a, b, acc[nt], 0, 0, 0);
                }
            }
        }
        // fold D (row = quad*4+reg = pair slot, col = n) from registers
        #pragma unroll
        for (int nt = 0; nt < 4; ++nt) {
            const int n = wave*64 + nt*16 + m;
            const float bb4 = b4[n];
            #pragma unroll
            for (int reg = 0; reg < 4; ++reg) {
                const int pr = pc*16 + quad*4 + reg;
                if (pr < npairs) {
                    const int rl2 = pl_rl[pr];
                    atomicMax(&cmU[rl2][n], encf(acc[nt][reg] + bb4));
                }
            }
        }
        __syncthreads();   // all U reads done before next chunk's U build
    }
    __syncthreads();   // all folds complete before cross-thread cmU reads
    // CMAX -> bf16 A-tile (col t owned); gemm's leading sync orders it
    #pragma unroll
    for (int rl2 = 0; rl2 < 16; ++rl2)
        U[rl2][t] = f2b(decf(cmU[rl2][t]));
    block_gemm256<3>(U, W5F, b5, nullptr, nullptr, out,
                     tgt, seed, r0, t);
}

extern "C" void kernel_launch(void* const* d_in, const int* in_sizes, int n_in,
                              void* d_out, int out_size, void* d_ws, size_t ws_size,
                              hipStream_t stream)
{
    (void)in_sizes; (void)n_in; (void)out_size; (void)ws_size;
    const float* tgt   = (const float*)d_in[0];
    const float* seed  = (const float*)d_in[1];
    const float* boxes = (const float*)d_in[2];
    const float* W1 = (const float*)d_in[3];
    const float* b1 = (const float*)d_in[4];
    const float* W2 = (const float*)d_in[5];
    const float* b2 = (const float*)d_in[6];
    const float* g2 = (const float*)d_in[7];
    const float* be2= (const float*)d_in[8];
    const float* W3 = (const float*)d_in[9];
    const float* b3 = (const float*)d_in[10];
    const float* W4 = (const float*)d_in[11];
    const float* b4 = (const float*)d_in[12];
    const float* W5 = (const float*)d_in[13];
    const float* b5 = (const float*)d_in[14];

    float* out_tgt  = (float*)d_out;                     // 8*1000*256 f32
    float* out_attn = out_tgt + (size_t)MROWS * DM;      // 8*1000*1000 f32

    // ws: WT (5x128KB bf16 frag-linear) | P (4MB bf16) | meta | bx4 | bar
    u16* WT   = (u16*)d_ws;
    u16* P    = WT + (size_t)5*WSZ;
    int* cnt  = (int*)(P + (size_t)MROWS*DM);
    int* inc0 = cnt + MROWS;
    int* idxs = inc0 + MROWS;
    float4* bx4 = (float4*)(idxs + MROWS*TOPK);          // 16B-aligned (5,135,360 % 16 == 0)
    float*  bar = (float*)(bx4 + MROWS);

    prep_k<<<112, 256, 0, stream>>>(W1, W2, W3, W4, W5, boxes, WT, bx4, bar);
    fused_iou_mlp_k<<<NTILE + MROWS/2, 256, 0, stream>>>(
        bx4, bar, seed, WT, b1, b2, g2, be2, tgt, P, out_attn, cnt, inc0, idxs);
    pairs_final_k<<<MROWS/16, 256, 0, stream>>>(P, WT, b3, b4, b5, cnt, inc0, idxs,
                                                tgt, seed, out_tgt);
}